// Round 1
// 213.777 us; speedup vs baseline: 1.0933x; 1.0933x over previous
//
#include <hip/hip_runtime.h>

#define BB 16
#define CIN 512
#define LLN 2048
#define EPSV 1e-5f

typedef __attribute__((ext_vector_type(8))) short bf16x8s;
typedef __attribute__((ext_vector_type(4))) float f32x4;

__device__ __forceinline__ unsigned short f2bf(float f) {
    union { float f; unsigned int i; } c; c.f = f;
    unsigned int x = c.i;
    unsigned int lsb = (x >> 16) & 1;
    x += 0x7fff + lsb;            // RNE
    return (unsigned short)(x >> 16);
}
__device__ __forceinline__ unsigned int pack2bf(float a, float b) {
    return (unsigned int)f2bf(a) | ((unsigned int)f2bf(b) << 16);
}

// async global->LDS, 16B per lane, LDS dest = wave-uniform base + lane*16
__device__ __forceinline__ void g2l16(const void* g, void* l) {
    typedef const __attribute__((address_space(1))) unsigned int GU;
    typedef __attribute__((address_space(3))) unsigned int LU;
    __builtin_amdgcn_global_load_lds((GU*)g, (LU*)l, 16, 0, 0);
}

// ---------------- Kernel 0: weight repack fp32 -> bf16 images ----------------
// Wpk layout: [cot 4][chunk 16] images of [t 3][co 64][ci 40] bf16 (32 real + 8 pad)
#define WIMG_U16 7680   // 3*64*40

__global__ __launch_bounds__(256) void prep_weights(
    const float* __restrict__ Wq, const float* __restrict__ Wk,
    const float* __restrict__ Wv, unsigned short* __restrict__ Wpk)
{
    int blk = blockIdx.x;             // 0..63 = cot*16 + chunk
    int cot = blk >> 4, chunk = blk & 15;
    int ci0 = chunk * 32;
    for (int i = threadIdx.x; i < WIMG_U16; i += 256) {
        int t = i / 2560, r = i % 2560, co = r / 40, ci = r % 40;
        float val = 0.f;
        int cop = cot * 64 + co;
        if (ci < 32) {
            int cig = ci0 + ci;
            if (cop < 64)        val = Wq[((size_t)cop * 512 + cig) * 3 + t];
            else if (cop < 80)   val = Wk[((size_t)(cop - 64) * 512 + cig) * 3 + t];
            else if (cop < 208)  val = Wv[((size_t)(cop - 80) * 512 + cig) * 3 + t];
        }
        Wpk[(size_t)blk * WIMG_U16 + i] = f2bf(val);
    }
}

// ---------------- Kernel 0b: x repack fp32 [b][ci][n] -> bf16 xpk ----------------
// xpk layout: [b][chunk 16][rp 2050][32 u16], rp = n+1 (rows 0 and 2049 are zero halo).
// Within a row, 16B group slot s holds logical ci-group (s ^ ((rp>>1)&3))  (pre-swizzled
// source so conv's linear global_load_lds + swizzled ds_read_b128 is bank-conflict-free).
__global__ __launch_bounds__(256) void prep_x(
    const float* __restrict__ x, unsigned short* __restrict__ xpk)
{
    const int nt = blockIdx.x;   // 0..7
    const int c  = blockIdx.y;   // 0..15
    const int b  = blockIdx.z;   // 0..15
    const int tid = threadIdx.x;
    const int n = nt * 256 + tid;
    const int rp = n + 1;
    const float* xb = x + ((size_t)b * CIN + (size_t)c * 32) * LLN + n;
    unsigned int row[16];
#pragma unroll
    for (int p = 0; p < 16; p++)
        row[p] = pack2bf(xb[(size_t)(2 * p) * LLN], xb[(size_t)(2 * p + 1) * LLN]);
    unsigned short* dst = xpk + ((size_t)(b * 16 + c) * 2050 + rp) * 32;
    const int sig = (rp >> 1) & 3;
#pragma unroll
    for (int s = 0; s < 4; s++) {
        int g = (s ^ sig) * 4;
        uint4 v = make_uint4(row[g], row[g + 1], row[g + 2], row[g + 3]);
        *(uint4*)(dst + s * 8) = v;
    }
    // zero halo rows rp=0 and rp=2049
    if (nt == 0 && tid < 4)
        *(uint4*)(xpk + ((size_t)(b * 16 + c) * 2050) * 32 + tid * 8) = make_uint4(0, 0, 0, 0);
    if (nt == 7 && tid < 4)
        *(uint4*)(xpk + ((size_t)(b * 16 + c) * 2050 + 2049) * 32 + tid * 8) = make_uint4(0, 0, 0, 0);
}

// ---------------- Kernel 1: MFMA conv (q|k|v) + BN ----------------
// Block: 64 co x 256 n, 4 waves (each 64co x 64n), 16 K-chunks of 32 ci.
// Staging is pure linear global_load_lds from prepacked bf16 images.
__global__ __launch_bounds__(256) void conv_mfma(
    const unsigned short* __restrict__ xpk, const unsigned short* __restrict__ Wpk,
    const float* __restrict__ qg, const float* __restrict__ qb,
    const float* __restrict__ qm, const float* __restrict__ qv,
    const float* __restrict__ vg, const float* __restrict__ vb,
    const float* __restrict__ vm, const float* __restrict__ vvar,
    float* __restrict__ qbuf, float* __restrict__ kbuf, float* __restrict__ vbuf)
{
    __shared__ __align__(16) unsigned short xT[258 * 32];   // 16512 B, row = 64B linear
    __shared__ __align__(16) unsigned short wA[WIMG_U16];   // 15360 B
    __shared__ float sscale[64], sshift[64];

    const int tid = threadIdx.x;
    const int wave = tid >> 6, lane = tid & 63;
    const int kq = lane >> 4, lm = lane & 15;
    const int n0 = blockIdx.x * 256;
    const int cot = blockIdx.y;          // 0..3 (64 co each)
    const int b = blockIdx.z;

    if (tid < 64) {
        int cop = cot * 64 + tid;
        float sc = 1.f, sh = 0.f;
        if (cop < 64) {
            float g = qg[cop], be = qb[cop], m = qm[cop], va = qv[cop];
            sc = g * rsqrtf(va + EPSV); sh = be - m * sc;
        } else if (cop >= 80 && cop < 208) {
            int cc = cop - 80;
            float g = vg[cc], be = vb[cc], m = vm[cc], va = vvar[cc];
            sc = g * rsqrtf(va + EPSV); sh = be - m * sc;
        }
        sscale[tid] = sc; sshift[tid] = sh;
    }

    f32x4 acc[4][4];
#pragma unroll
    for (int i = 0; i < 4; i++)
#pragma unroll
        for (int j = 0; j < 4; j++) acc[i][j] = (f32x4){0.f, 0.f, 0.f, 0.f};

    for (int chunk = 0; chunk < 16; chunk++) {
        __syncthreads();                 // previous chunk's LDS reads done
        const unsigned short* wsrc = Wpk + (size_t)(cot * 16 + chunk) * WIMG_U16;
        const unsigned short* xsrc = xpk + ((size_t)(b * 16 + chunk) * 2050 + n0) * 32;
        for (int i = tid; i < 960; i += 256)          // 15360 B weights
            g2l16(wsrc + (size_t)i * 8, wA + i * 8);
        for (int i = tid; i < 1032; i += 256)         // 16512 B x rows n0-1..n0+256
            g2l16(xsrc + (size_t)i * 8, xT + i * 8);
        asm volatile("s_waitcnt vmcnt(0)" ::: "memory");
        __syncthreads();

#pragma unroll
        for (int t = 0; t < 3; t++) {
            bf16x8s aF[4];
#pragma unroll
            for (int cf = 0; cf < 4; cf++)
                aF[cf] = *(const bf16x8s*)&wA[t * 2560 + (cf * 16 + lm) * 40 + kq * 8];
#pragma unroll
            for (int fn = 0; fn < 4; fn++) {
                int lr = wave * 64 + fn * 16 + lm + t;
                int grp = kq ^ ((lr >> 1) & 3);       // matches prep_x pre-swizzle
                bf16x8s bF = *(const bf16x8s*)&xT[lr * 32 + grp * 8];
#pragma unroll
                for (int cf = 0; cf < 4; cf++)
                    acc[cf][fn] = __builtin_amdgcn_mfma_f32_16x16x32_bf16(
                        aF[cf], bF, acc[cf][fn], 0, 0, 0);
            }
        }
    }

    // epilogue: C layout col=lane&15 (n), row=(lane>>4)*4+reg (co)
#pragma unroll
    for (int cf = 0; cf < 4; cf++) {
#pragma unroll
        for (int fn = 0; fn < 4; fn++) {
#pragma unroll
            for (int r = 0; r < 4; r++) {
                int col = cf * 16 + kq * 4 + r;        // co_local 0..63
                int cop = cot * 64 + col;
                if (cop >= 208) continue;
                float val = acc[cf][fn][r] * sscale[col] + sshift[col];
                int nout = n0 + wave * 64 + fn * 16 + lm;
                if (cop < 64)
                    qbuf[((size_t)b * 64 + cop) * LLN + nout] = val;
                else if (cop < 80)
                    kbuf[((size_t)b * 16 + (cop - 64)) * LLN + nout] = val;
                else
                    vbuf[((size_t)b * 128 + (cop - 80)) * LLN + nout] = val;
            }
        }
    }
}

// ---------------- Kernel 2: softmax over n, in place on kbuf ----------------
__global__ __launch_bounds__(256) void softmax_kernel(float* __restrict__ kbuf)
{
    const int row = blockIdx.x;                  // B*16 = 256 rows
    float* p = kbuf + (size_t)row * LLN;
    const int tid = threadIdx.x;
    __shared__ float red[256];

    float vals[8];
    float vmax = -1e30f;
#pragma unroll
    for (int j = 0; j < 8; j++) {
        vals[j] = p[tid + j * 256];
        vmax = fmaxf(vmax, vals[j]);
    }
    red[tid] = vmax;
    __syncthreads();
    for (int s = 128; s > 0; s >>= 1) {
        if (tid < s) red[tid] = fmaxf(red[tid], red[tid + s]);
        __syncthreads();
    }
    float m = red[0];
    __syncthreads();
    float sum = 0.f;
#pragma unroll
    for (int j = 0; j < 8; j++) {
        vals[j] = __expf(vals[j] - m);
        sum += vals[j];
    }
    red[tid] = sum;
    __syncthreads();
    for (int s = 128; s > 0; s >>= 1) {
        if (tid < s) red[tid] += red[tid + s];
        __syncthreads();
    }
    float inv = 1.f / red[0];
#pragma unroll
    for (int j = 0; j < 8; j++) p[tid + j * 256] = vals[j] * inv;
}

// ---------------- Kernel 3: lambda_c[b][k][v] = sum_n sm*v ----------------
// block = (b, v-group-of-8); wave = 4 k-rows. vbuf rows read once per block
// (shared across the wave's 4 k), sm rows read once per k.
__global__ __launch_bounds__(256) void lambdac_kernel(
    const float* __restrict__ sm, const float* __restrict__ vbuf,
    float* __restrict__ lc)
{
    const int wave = threadIdx.x >> 6;
    const int lane = threadIdx.x & 63;
    const int b = blockIdx.x >> 4;
    const int vg = blockIdx.x & 15;
    const float* ps = sm + ((size_t)b * 16 + wave * 4) * LLN;
    const float* pv = vbuf + ((size_t)b * 128 + vg * 8) * LLN;
    float acc[4][8];
#pragma unroll
    for (int k = 0; k < 4; k++)
#pragma unroll
        for (int v = 0; v < 8; v++) acc[k][v] = 0.f;
#pragma unroll
    for (int j = 0; j < 8; j++) {
        int n = (j * 64 + lane) * 4;
        float4 s4[4], v4[8];
#pragma unroll
        for (int k = 0; k < 4; k++) s4[k] = *(const float4*)&ps[(size_t)k * LLN + n];
#pragma unroll
        for (int v = 0; v < 8; v++) v4[v] = *(const float4*)&pv[(size_t)v * LLN + n];
#pragma unroll
        for (int k = 0; k < 4; k++)
#pragma unroll
            for (int v = 0; v < 8; v++)
                acc[k][v] += s4[k].x * v4[v].x + s4[k].y * v4[v].y
                           + s4[k].z * v4[v].z + s4[k].w * v4[v].w;
    }
#pragma unroll
    for (int k = 0; k < 4; k++)
#pragma unroll
        for (int v = 0; v < 8; v++) {
#pragma unroll
            for (int off = 32; off > 0; off >>= 1)
                acc[k][v] += __shfl_xor(acc[k][v], off, 64);
        }
    if (lane == 0) {
#pragma unroll
        for (int k = 0; k < 4; k++)
#pragma unroll
            for (int v = 0; v < 8; v++)
                lc[((size_t)b * 16 + wave * 4 + k) * 128 + vg * 8 + v] = acc[k][v];
    }
}

// ---------------- Kernel 4: output ----------------
// out[b][h*128+v][n] = sum_k q[b][h*16+k][n]*lc[b][k][v] + (sum_k q*emb[k]) * v[b][v][n]
#define FT_N 256
__global__ __launch_bounds__(256) void final_kernel(
    const float* __restrict__ qbuf, const float* __restrict__ vbuf,
    const float* __restrict__ lc, const float* __restrict__ emb,
    float* __restrict__ out)
{
    __shared__ float qs[16][FT_N];
    __shared__ float lcs[16][128];
    __shared__ float es[16];
    const int tid = threadIdx.x;
    const int n0 = blockIdx.x * FT_N;   // 8 tiles
    const int h = blockIdx.y;           // 4
    const int b = blockIdx.z;           // 16

    for (int i = tid; i < 16 * FT_N; i += 256) {
        int r = i >> 8, c = i & 255;
        qs[r][c] = qbuf[((size_t)b * 64 + h * 16 + r) * LLN + n0 + c];
    }
    for (int i = tid; i < 16 * 128; i += 256)
        lcs[i >> 7][i & 127] = lc[(size_t)b * 2048 + i];
    if (tid < 16) es[tid] = emb[tid];
    __syncthreads();

    const int n = n0 + tid;
    float q[16];
    float s = 0.f;
#pragma unroll
    for (int k2 = 0; k2 < 16; k2++) {
        q[k2] = qs[k2][tid];
        s += q[k2] * es[k2];
    }
    const float* pv = vbuf + (size_t)b * 128 * LLN + n;
    float* po = out + ((size_t)b * 512 + h * 128) * LLN + n;
    for (int v = 0; v < 128; v++) {
        float lam = 0.f;
#pragma unroll
        for (int k2 = 0; k2 < 16; k2++) lam += q[k2] * lcs[k2][v];
        float vvv = pv[(size_t)v * LLN];
        po[(size_t)v * LLN] = lam + s * vvv;
    }
}

extern "C" void kernel_launch(void* const* d_in, const int* in_sizes, int n_in,
                              void* d_out, int out_size, void* d_ws, size_t ws_size,
                              hipStream_t stream)
{
    const float* x   = (const float*)d_in[0];
    const float* Wq  = (const float*)d_in[1];
    const float* qg  = (const float*)d_in[2];
    const float* qb  = (const float*)d_in[3];
    const float* qm  = (const float*)d_in[4];
    const float* qv  = (const float*)d_in[5];
    const float* Wk  = (const float*)d_in[6];
    const float* Wv  = (const float*)d_in[7];
    const float* vg  = (const float*)d_in[8];
    const float* vb  = (const float*)d_in[9];
    const float* vm  = (const float*)d_in[10];
    const float* vva = (const float*)d_in[11];
    const float* emb = (const float*)d_in[12];
    float* out = (float*)d_out;

    float* qbuf = (float*)d_ws;                         // 16*64*2048 f32
    float* kbuf = qbuf + (size_t)BB * 64 * LLN;         // 16*16*2048
    float* vbuf = kbuf + (size_t)BB * 16 * LLN;         // 16*128*2048
    float* lcb  = vbuf + (size_t)BB * 128 * LLN;        // 16*16*128
    unsigned short* Wpk = (unsigned short*)(lcb + (size_t)BB * 16 * 128);   // 64*7680 u16
    unsigned short* xpk = Wpk + (size_t)64 * WIMG_U16;  // 256*2050*32 u16 (~33.6 MB)

    hipLaunchKernelGGL(prep_weights, dim3(64), dim3(256), 0, stream, Wq, Wk, Wv, Wpk);

    hipLaunchKernelGGL(prep_x, dim3(8, 16, 16), dim3(256), 0, stream, x, xpk);

    hipLaunchKernelGGL(conv_mfma, dim3(8, 4, 16), dim3(256), 0, stream,
                       xpk, Wpk, qg, qb, qm, qv, vg, vb, vm, vva,
                       qbuf, kbuf, vbuf);

    hipLaunchKernelGGL(softmax_kernel, dim3(BB * 16), dim3(256), 0, stream, kbuf);

    hipLaunchKernelGGL(lambdac_kernel, dim3(256), dim3(256), 0, stream,
                       kbuf, vbuf, lcb);

    hipLaunchKernelGGL(final_kernel, dim3(LLN / FT_N, 4, BB), dim3(256), 0, stream,
                       qbuf, vbuf, lcb, emb, out);
}

// Round 2
// 204.208 us; speedup vs baseline: 1.1446x; 1.0469x over previous
//
#include <hip/hip_runtime.h>

#define BB 16
#define CIN 512
#define LLN 2048
#define EPSV 1e-5f

typedef __attribute__((ext_vector_type(8))) short bf16x8s;
typedef __attribute__((ext_vector_type(4))) float f32x4;

__device__ __forceinline__ unsigned short f2bf(float f) {
    union { float f; unsigned int i; } c; c.f = f;
    unsigned int x = c.i;
    unsigned int lsb = (x >> 16) & 1;
    x += 0x7fff + lsb;            // RNE
    return (unsigned short)(x >> 16);
}
__device__ __forceinline__ unsigned int pack2bf(float a, float b) {
    return (unsigned int)f2bf(a) | ((unsigned int)f2bf(b) << 16);
}

// async global->LDS, 16B per lane, LDS dest = wave-uniform base + lane*16
__device__ __forceinline__ void g2l16(const void* g, void* l) {
    typedef const __attribute__((address_space(1))) unsigned int GU;
    typedef __attribute__((address_space(3))) unsigned int LU;
    __builtin_amdgcn_global_load_lds((GU*)g, (LU*)l, 16, 0, 0);
}

// ---------------- Kernel 0: prep (x repack + weight repack, one dispatch) ----
// xpk: [b][chunk 16][rp 2050][32 u16], rp = n+1 (rows 0,2049 zero halo); within a
// row the 16B group slot s holds logical ci-group (s ^ ((rp>>1)&3)).
// Wpk: [cot 4][chunk 16] images of [t 3][cf 4][lane 64][e 8] bf16 (6144 u16):
//   lane = kq*16+lm holds W[co=cot*64+cf*16+lm][ci0+kq*8+e][t]  (frag-contiguous).
#define WIMG_U16 6144

__global__ __launch_bounds__(256) void prep_all(
    const float* __restrict__ x,
    const float* __restrict__ Wq, const float* __restrict__ Wk,
    const float* __restrict__ Wv,
    unsigned short* __restrict__ xpk, unsigned short* __restrict__ Wpk)
{
    const int tid = threadIdx.x;
    if (blockIdx.z < 16) {
        // ---- x repack ----
        const int nt = blockIdx.x;   // 0..7
        const int c  = blockIdx.y;   // 0..15
        const int b  = blockIdx.z;   // 0..15
        const int n = nt * 256 + tid;
        const int rp = n + 1;
        const float* xb = x + ((size_t)b * CIN + (size_t)c * 32) * LLN + n;
        unsigned int row[16];
#pragma unroll
        for (int p = 0; p < 16; p++)
            row[p] = pack2bf(xb[(size_t)(2 * p) * LLN], xb[(size_t)(2 * p + 1) * LLN]);
        unsigned short* dst = xpk + ((size_t)(b * 16 + c) * 2050 + rp) * 32;
        const int sig = (rp >> 1) & 3;
#pragma unroll
        for (int s = 0; s < 4; s++) {
            int g = (s ^ sig) * 4;
            *(uint4*)(dst + s * 8) = make_uint4(row[g], row[g + 1], row[g + 2], row[g + 3]);
        }
        if (nt == 0 && tid < 4)
            *(uint4*)(xpk + ((size_t)(b * 16 + c) * 2050) * 32 + tid * 8) = make_uint4(0, 0, 0, 0);
        if (nt == 7 && tid < 4)
            *(uint4*)(xpk + ((size_t)(b * 16 + c) * 2050 + 2049) * 32 + tid * 8) = make_uint4(0, 0, 0, 0);
    } else {
        // ---- weight repack: 128 blocks, half an image each ----
        const int wblk = blockIdx.y * 8 + blockIdx.x;   // 0..127
        const int img = wblk >> 1, half = wblk & 1;     // img = cot*16 + chunk
        const int cot = img >> 4, chunk = img & 15;
        const int ci0 = chunk * 32;
        for (int i = half * 3072 + tid; i < half * 3072 + 3072; i += 256) {
            int t = i >> 11, r = i & 2047;
            int cf = r >> 9, lane = (r >> 3) & 63, e = i & 7;
            int lm = lane & 15, kq = lane >> 4;
            int cop = cot * 64 + cf * 16 + lm;
            int cig = ci0 + kq * 8 + e;
            float val = 0.f;
            if (cop < 64)        val = Wq[((size_t)cop * 512 + cig) * 3 + t];
            else if (cop < 80)   val = Wk[((size_t)(cop - 64) * 512 + cig) * 3 + t];
            else if (cop < 208)  val = Wv[((size_t)(cop - 80) * 512 + cig) * 3 + t];
            Wpk[(size_t)img * WIMG_U16 + i] = f2bf(val);
        }
    }
}

// ---------------- Kernel 1: MFMA conv (q|k|v) + BN, double-buffered ----------
// Block: 64 co x 256 n, 4 waves (each 64co x 64n), 16 K-chunks of 32 ci.
// 2-phase pipeline: issue chunk t+1's global_load_lds, compute chunk t,
// vmcnt(0)+barrier once per chunk (loads complete under the MFMAs).
__global__ __launch_bounds__(256) void conv_mfma(
    const unsigned short* __restrict__ xpk, const unsigned short* __restrict__ Wpk,
    const float* __restrict__ qg, const float* __restrict__ qb,
    const float* __restrict__ qm, const float* __restrict__ qv,
    const float* __restrict__ vg, const float* __restrict__ vb,
    const float* __restrict__ vm, const float* __restrict__ vvar,
    float* __restrict__ qbuf, float* __restrict__ kbuf, float* __restrict__ vbuf)
{
    __shared__ __align__(16) unsigned short xT[2][258 * 32];   // 2 x 16512 B
    __shared__ __align__(16) unsigned short wA[2][WIMG_U16];   // 2 x 12288 B
    __shared__ float sscale[64], sshift[64];

    const int tid = threadIdx.x;
    const int wave = tid >> 6, lane = tid & 63;
    const int kq = lane >> 4, lm = lane & 15;
    const int n0 = blockIdx.x * 256;
    const int cot = blockIdx.y;          // 0..3 (64 co each)
    const int b = blockIdx.z;

    const unsigned short* xpanel = xpk + ((size_t)b * 16 * 2050 + n0) * 32;
    const unsigned short* wbase  = Wpk + (size_t)cot * 16 * WIMG_U16;

#define STAGE(buf, chunk)                                                      \
    {                                                                          \
        const unsigned short* wsrc = wbase + (size_t)(chunk) * WIMG_U16;       \
        const unsigned short* xsrc = xpanel + (size_t)(chunk) * 2050 * 32;     \
        for (int i = tid; i < 768; i += 256)  g2l16(wsrc + i * 8, &wA[buf][i * 8]); \
        for (int i = tid; i < 1032; i += 256) g2l16(xsrc + i * 8, &xT[buf][i * 8]); \
    }

    STAGE(0, 0)

    if (tid < 64) {                      // BN prep overlaps prologue loads
        int cop = cot * 64 + tid;
        float sc = 1.f, sh = 0.f;
        if (cop < 64) {
            float g = qg[cop], be = qb[cop], m = qm[cop], va = qv[cop];
            sc = g * rsqrtf(va + EPSV); sh = be - m * sc;
        } else if (cop >= 80 && cop < 208) {
            int cc = cop - 80;
            float g = vg[cc], be = vb[cc], m = vm[cc], va = vvar[cc];
            sc = g * rsqrtf(va + EPSV); sh = be - m * sc;
        }
        sscale[tid] = sc; sshift[tid] = sh;
    }

    f32x4 acc[4][4];
#pragma unroll
    for (int i = 0; i < 4; i++)
#pragma unroll
        for (int j = 0; j < 4; j++) acc[i][j] = (f32x4){0.f, 0.f, 0.f, 0.f};

    asm volatile("s_waitcnt vmcnt(0)" ::: "memory");
    __syncthreads();

    for (int chunk = 0; chunk < 16; chunk++) {
        const int cur = chunk & 1;
        if (chunk < 15) STAGE(cur ^ 1, chunk + 1)

#pragma unroll
        for (int t = 0; t < 3; t++) {
            bf16x8s aF[4];
#pragma unroll
            for (int cf = 0; cf < 4; cf++)
                aF[cf] = *(const bf16x8s*)&wA[cur][((t * 4 + cf) * 64 + lane) * 8];
#pragma unroll
            for (int fn = 0; fn < 4; fn++) {
                int lr = wave * 64 + fn * 16 + lm + t;
                int grp = kq ^ ((lr >> 1) & 3);       // matches prep pre-swizzle
                bf16x8s bF = *(const bf16x8s*)&xT[cur][lr * 32 + grp * 8];
#pragma unroll
                for (int cf = 0; cf < 4; cf++)
                    acc[cf][fn] = __builtin_amdgcn_mfma_f32_16x16x32_bf16(
                        aF[cf], bF, acc[cf][fn], 0, 0, 0);
            }
        }
        asm volatile("s_waitcnt vmcnt(0)" ::: "memory");
        __syncthreads();
    }
#undef STAGE

    // epilogue: C layout col=lane&15 (n), row=(lane>>4)*4+reg (co)
#pragma unroll
    for (int cf = 0; cf < 4; cf++) {
#pragma unroll
        for (int fn = 0; fn < 4; fn++) {
#pragma unroll
            for (int r = 0; r < 4; r++) {
                int col = cf * 16 + kq * 4 + r;        // co_local 0..63
                int cop = cot * 64 + col;
                if (cop >= 208) continue;
                float val = acc[cf][fn][r] * sscale[col] + sshift[col];
                int nout = n0 + wave * 64 + fn * 16 + lm;
                if (cop < 64)
                    qbuf[((size_t)b * 64 + cop) * LLN + nout] = val;
                else if (cop < 80)
                    kbuf[((size_t)b * 16 + (cop - 64)) * LLN + nout] = val;
                else
                    vbuf[((size_t)b * 128 + (cop - 80)) * LLN + nout] = val;
            }
        }
    }
}

// ---------------- Kernel 2: fused softmax + lambda_c ----------------
// lambda_c[b][k][v] = sum_n softmax(kbuf[b][k])[n] * vbuf[b][v][n]
// block = (b, v-group-of-4); wave owns 4 k-rows fully -> online max + exp-sum,
// normalize at the end. Softmax kernel eliminated.
__global__ __launch_bounds__(256) void lambdac_kernel(
    const float* __restrict__ kb, const float* __restrict__ vbuf,
    float* __restrict__ lcb)
{
    const int wave = threadIdx.x >> 6;
    const int lane = threadIdx.x & 63;
    const int b = blockIdx.x >> 5;
    const int vg = blockIdx.x & 31;
    const float* ps = kb + ((size_t)b * 16 + wave * 4) * LLN;
    const float* pv = vbuf + ((size_t)b * 128 + vg * 4) * LLN;

    // pass A: row max
    float m[4] = {-1e30f, -1e30f, -1e30f, -1e30f};
#pragma unroll
    for (int j = 0; j < 8; j++) {
        int n = (j * 64 + lane) * 4;
#pragma unroll
        for (int k = 0; k < 4; k++) {
            float4 s4 = *(const float4*)&ps[(size_t)k * LLN + n];
            m[k] = fmaxf(m[k], fmaxf(fmaxf(s4.x, s4.y), fmaxf(s4.z, s4.w)));
        }
    }
#pragma unroll
    for (int k = 0; k < 4; k++)
#pragma unroll
        for (int off = 32; off > 0; off >>= 1)
            m[k] = fmaxf(m[k], __shfl_xor(m[k], off, 64));

    // pass B: exp, sum, and v-accumulate
    float sum[4] = {0.f, 0.f, 0.f, 0.f};
    float acc[4][4];
#pragma unroll
    for (int k = 0; k < 4; k++)
#pragma unroll
        for (int v = 0; v < 4; v++) acc[k][v] = 0.f;
#pragma unroll
    for (int j = 0; j < 8; j++) {
        int n = (j * 64 + lane) * 4;
        float4 e4[4];
#pragma unroll
        for (int k = 0; k < 4; k++) {
            float4 s4 = *(const float4*)&ps[(size_t)k * LLN + n];
            e4[k].x = __expf(s4.x - m[k]);
            e4[k].y = __expf(s4.y - m[k]);
            e4[k].z = __expf(s4.z - m[k]);
            e4[k].w = __expf(s4.w - m[k]);
            sum[k] += e4[k].x + e4[k].y + e4[k].z + e4[k].w;
        }
#pragma unroll
        for (int v = 0; v < 4; v++) {
            float4 v4 = *(const float4*)&pv[(size_t)v * LLN + n];
#pragma unroll
            for (int k = 0; k < 4; k++)
                acc[k][v] += e4[k].x * v4.x + e4[k].y * v4.y
                           + e4[k].z * v4.z + e4[k].w * v4.w;
        }
    }
#pragma unroll
    for (int k = 0; k < 4; k++) {
#pragma unroll
        for (int off = 32; off > 0; off >>= 1)
            sum[k] += __shfl_xor(sum[k], off, 64);
#pragma unroll
        for (int v = 0; v < 4; v++)
#pragma unroll
            for (int off = 32; off > 0; off >>= 1)
                acc[k][v] += __shfl_xor(acc[k][v], off, 64);
    }
    if (lane == 0) {
#pragma unroll
        for (int k = 0; k < 4; k++) {
            float inv = 1.f / sum[k];
#pragma unroll
            for (int v = 0; v < 4; v++)
                lcb[((size_t)b * 16 + wave * 4 + k) * 128 + vg * 4 + v] = acc[k][v] * inv;
        }
    }
}

// ---------------- Kernel 3: output, all 4 heads fused ----------------
// out[b][h*128+v][n] = sum_k q[b][h*16+k][n]*lc[b][k][v] + (sum_k q*emb[k])*v[b][v][n]
// block = (n-tile 64, b); wave = head. vbuf read ONCE (waves share via L1).
__global__ __launch_bounds__(256) void final_kernel(
    const float* __restrict__ qbuf, const float* __restrict__ vbuf,
    const float* __restrict__ lcb, const float* __restrict__ emb,
    float* __restrict__ out)
{
    __shared__ float lcsT[128][16];   // transposed: row v, 16 k contiguous
    __shared__ float es[16];
    const int tid = threadIdx.x;
    const int h = tid >> 6, nl = tid & 63;
    const int n0 = blockIdx.x * 64;   // 32 tiles
    const int b = blockIdx.y;

    for (int i = tid; i < 2048; i += 256)
        lcsT[i >> 4][i & 15] = lcb[(size_t)b * 2048 + (size_t)(i & 15) * 128 + (i >> 4)];
    if (tid < 16) es[tid] = emb[tid];
    __syncthreads();

    const int n = n0 + nl;
    const float* pq = qbuf + ((size_t)b * 64 + h * 16) * LLN + n;
    float4 q4[4];
#pragma unroll
    for (int kk = 0; kk < 4; kk++) {
        q4[kk].x = pq[(size_t)(kk * 4 + 0) * LLN];
        q4[kk].y = pq[(size_t)(kk * 4 + 1) * LLN];
        q4[kk].z = pq[(size_t)(kk * 4 + 2) * LLN];
        q4[kk].w = pq[(size_t)(kk * 4 + 3) * LLN];
    }
    float s = 0.f;
#pragma unroll
    for (int kk = 0; kk < 4; kk++)
        s += q4[kk].x * es[kk * 4] + q4[kk].y * es[kk * 4 + 1]
           + q4[kk].z * es[kk * 4 + 2] + q4[kk].w * es[kk * 4 + 3];

    const float* pv = vbuf + (size_t)b * 128 * LLN + n;
    float* po = out + ((size_t)b * 512 + h * 128) * LLN + n;
    for (int v = 0; v < 128; v++) {
        float4 c0 = *(const float4*)&lcsT[v][0];
        float4 c1 = *(const float4*)&lcsT[v][4];
        float4 c2 = *(const float4*)&lcsT[v][8];
        float4 c3 = *(const float4*)&lcsT[v][12];
        float lam = q4[0].x * c0.x + q4[0].y * c0.y + q4[0].z * c0.z + q4[0].w * c0.w
                  + q4[1].x * c1.x + q4[1].y * c1.y + q4[1].z * c1.z + q4[1].w * c1.w
                  + q4[2].x * c2.x + q4[2].y * c2.y + q4[2].z * c2.z + q4[2].w * c2.w
                  + q4[3].x * c3.x + q4[3].y * c3.y + q4[3].z * c3.z + q4[3].w * c3.w;
        float vvv = pv[(size_t)v * LLN];
        po[(size_t)v * LLN] = lam + s * vvv;
    }
}

extern "C" void kernel_launch(void* const* d_in, const int* in_sizes, int n_in,
                              void* d_out, int out_size, void* d_ws, size_t ws_size,
                              hipStream_t stream)
{
    const float* x   = (const float*)d_in[0];
    const float* Wq  = (const float*)d_in[1];
    const float* qg  = (const float*)d_in[2];
    const float* qb  = (const float*)d_in[3];
    const float* qm  = (const float*)d_in[4];
    const float* qv  = (const float*)d_in[5];
    const float* Wk  = (const float*)d_in[6];
    const float* Wv  = (const float*)d_in[7];
    const float* vg  = (const float*)d_in[8];
    const float* vb  = (const float*)d_in[9];
    const float* vm  = (const float*)d_in[10];
    const float* vva = (const float*)d_in[11];
    const float* emb = (const float*)d_in[12];
    float* out = (float*)d_out;

    float* qbuf = (float*)d_ws;                         // 16*64*2048 f32
    float* kbuf = qbuf + (size_t)BB * 64 * LLN;         // 16*16*2048
    float* vbuf = kbuf + (size_t)BB * 16 * LLN;         // 16*128*2048
    float* lcb  = vbuf + (size_t)BB * 128 * LLN;        // 16*16*128
    unsigned short* Wpk = (unsigned short*)(lcb + (size_t)BB * 16 * 128);   // 64*6144 u16
    unsigned short* xpk = Wpk + (size_t)64 * WIMG_U16;  // 256*2050*32 u16 (~33.6 MB)

    hipLaunchKernelGGL(prep_all, dim3(8, 16, 17), dim3(256), 0, stream,
                       x, Wq, Wk, Wv, xpk, Wpk);

    hipLaunchKernelGGL(conv_mfma, dim3(8, 4, 16), dim3(256), 0, stream,
                       xpk, Wpk, qg, qb, qm, qv, vg, vb, vm, vva,
                       qbuf, kbuf, vbuf);

    hipLaunchKernelGGL(lambdac_kernel, dim3(512), dim3(256), 0, stream,
                       kbuf, vbuf, lcb);

    hipLaunchKernelGGL(final_kernel, dim3(32, BB), dim3(256), 0, stream,
                       qbuf, vbuf, lcb, emb, out);
}